// Round 1
// baseline (561.721 us; speedup 1.0000x reference)
//
#include <hip/hip_runtime.h>
#include <math.h>

#define NP 4096     // GRID*GRID RF positions / grid points
#define NA 256      // stim channels
#define BP 32       // p-tile per block
#define BA 128      // a-tile per block
#define GB 32       // g (K) chunk per LDS stage
#define LFS 36      // lF row stride (pad: 16B-aligned rows, benign write conflict)

// ---------------------------------------------------------------------------
// Setup: per-p 1D Gaussian tables (normalization folded in) + attention field.
// gtab layout: [field f=0(rf),1(ss),2(sf)] [x=0,y=1] [p:4096] [idx:64]
// ---------------------------------------------------------------------------
__global__ void setup_kernel(const float* __restrict__ pscale,
                             const float* __restrict__ pasig,
                             const float* __restrict__ pagain,
                             const float* __restrict__ pssf,
                             const float* __restrict__ psff,
                             float* __restrict__ gtab,
                             float* __restrict__ attf)
{
    int p = blockIdx.x;       // RF index
    int j = threadIdx.x;      // 0..63, one wave
    const float step = 20.0f / 63.0f;
    float cx = -10.0f + step * (float)(p & 63);
    float cy = -10.0f + step * (float)(p >> 6);
    float coord = -10.0f + step * (float)j;

    float sig0 = 0.07f + pscale[0] * sqrtf(cx * cx + cy * cy);
    float fac0 = 1.0f, fac1 = pssf[0], fac2 = psff[0];

    float dx = coord - cx;
    float dy = coord - cy;

    #pragma unroll
    for (int f = 0; f < 3; ++f) {
        float s = sig0 * (f == 0 ? fac0 : (f == 1 ? fac1 : fac2));
        float inv = 1.0f / (2.0f * s * s);
        float gx = expf(-dx * dx * inv);
        float gy = expf(-dy * dy * inv);
        // wave(64)-wide sum
        float sx = gx, sy = gy;
        #pragma unroll
        for (int off = 32; off > 0; off >>= 1) {
            sx += __shfl_down(sx, off);
            sy += __shfl_down(sy, off);
        }
        sx = __shfl(sx, 0);
        sy = __shfl(sy, 0);
        float* bx = gtab + (size_t)f * 2 * NP * 64;
        bx[p * 64 + j] = gx / sx;            // gxn[p][j]
        bx[NP * 64 + p * 64 + j] = gy / sy;  // gyn[p][i]
    }
    if (j == 0) {
        float as = pasig[0];
        float d2 = (cx - 3.0f) * (cx - 3.0f) + cy * cy;
        attf[p] = pagain[0] * expf(-d2 / (2.0f * as * as)) + 1.0f;
    }
}

// ---------------------------------------------------------------------------
// C[p,a] = sum_g F[g,p] * B[g,a],  F[g,p] = gyn[p][g>>6] * gxn[p][g&63]
// MODE 0: C = dot * attf[p]                      (numerator)
// MODE 1: C = dot; C2 = num/(dot + 0.5)          (surround, predicted_neural)
// MODE 2: C = dot                                (predicted_voxel)
// Block: 256 threads, tile BP=32 x BA=128, micro 4p x 4a. Grid 128x2 = 256.
// ---------------------------------------------------------------------------
template <int MODE>
__global__ __launch_bounds__(256)
void field_gemm(const float* __restrict__ gx,
                const float* __restrict__ gy,
                const float* __restrict__ B,
                const float* __restrict__ attf,
                const float* __restrict__ num,
                float* __restrict__ C,
                float* __restrict__ C2)
{
    __shared__ float lx[BP * 64];       // gxn rows for this p-tile
    __shared__ float ly[BP * 64];       // gyn rows
    __shared__ float lB[GB * BA];       // B chunk [gg][a]
    __shared__ float lF[GB * LFS];      // F chunk [gg][p] (padded rows)

    int t = threadIdx.x;
    int p0 = blockIdx.x * BP;
    int a0 = blockIdx.y * BA;

    // one-time load of the p-tile's 1D tables (contiguous, coalesced)
    for (int q = t; q < BP * 64 / 4; q += 256) {
        ((float4*)lx)[q] = ((const float4*)(gx + (size_t)p0 * 64))[q];
        ((float4*)ly)[q] = ((const float4*)(gy + (size_t)p0 * 64))[q];
    }

    float acc[4][4] = {{0.0f}};
    int tp = t >> 5;   // 0..7  -> p rows  p0 + tp*4 ..+3
    int ta = t & 31;   // 0..31 -> a cols  a0 + ta*4 ..+3

    for (int g0 = 0; g0 < NP; g0 += GB) {
        __syncthreads();
        // stage B chunk: GB*BA floats = 1024 float4, 4 per thread (coalesced)
        #pragma unroll
        for (int r = 0; r < 4; ++r) {
            int q = t + r * 256;
            int gg = q >> 5, aa = q & 31;
            ((float4*)lB)[q] =
                *((const float4*)(B + (size_t)(g0 + gg) * NA + a0) + aa);
        }
        // stage F chunk: within a chunk i is constant -> ly broadcast, lx stride-1
        #pragma unroll
        for (int r = 0; r < 4; ++r) {
            int q = t + r * 256;
            int gg = q & 31, pp = q >> 5;
            int g = g0 + gg;
            int gi = g >> 6, gj = g & 63;
            lF[gg * LFS + pp] = ly[pp * 64 + gi] * lx[pp * 64 + gj];
        }
        __syncthreads();
        #pragma unroll
        for (int gg = 0; gg < GB; ++gg) {
            float4 f4 = *(const float4*)&lF[gg * LFS + tp * 4];
            float4 b4 = *(const float4*)&lB[gg * BA + ta * 4];
            acc[0][0] += f4.x * b4.x; acc[0][1] += f4.x * b4.y;
            acc[0][2] += f4.x * b4.z; acc[0][3] += f4.x * b4.w;
            acc[1][0] += f4.y * b4.x; acc[1][1] += f4.y * b4.y;
            acc[1][2] += f4.y * b4.z; acc[1][3] += f4.y * b4.w;
            acc[2][0] += f4.z * b4.x; acc[2][1] += f4.z * b4.y;
            acc[2][2] += f4.z * b4.z; acc[2][3] += f4.z * b4.w;
            acc[3][0] += f4.w * b4.x; acc[3][1] += f4.w * b4.y;
            acc[3][2] += f4.w * b4.z; acc[3][3] += f4.w * b4.w;
        }
    }

    int prow = p0 + tp * 4;
    int acol = a0 + ta * 4;
    #pragma unroll
    for (int i = 0; i < 4; ++i) {
        size_t off = (size_t)(prow + i) * NA + acol;
        float4 v = make_float4(acc[i][0], acc[i][1], acc[i][2], acc[i][3]);
        if (MODE == 0) {
            float s = attf[prow + i];
            v.x *= s; v.y *= s; v.z *= s; v.w *= s;
            *(float4*)(C + off) = v;
        } else if (MODE == 1) {
            *(float4*)(C + off) = v;
            float4 n = *(const float4*)(num + off);
            float4 pn;
            pn.x = n.x / (v.x + 0.5f);
            pn.y = n.y / (v.y + 0.5f);
            pn.z = n.z / (v.z + 0.5f);
            pn.w = n.w / (v.w + 0.5f);
            *(float4*)(C2 + off) = pn;
        } else {
            *(float4*)(C + off) = v;
        }
    }
}

extern "C" void kernel_launch(void* const* d_in, const int* in_sizes, int n_in,
                              void* d_out, int out_size, void* d_ws, size_t ws_size,
                              hipStream_t stream)
{
    const float* stim   = (const float*)d_in[0];
    const float* pscale = (const float*)d_in[1];
    const float* pasig  = (const float*)d_in[2];
    const float* pagain = (const float*)d_in[3];
    const float* pssf   = (const float*)d_in[4];
    const float* psff   = (const float*)d_in[5];

    float* out  = (float*)d_out;
    float* num  = out;                          // output 0: numerator
    float* surr = out + (size_t)NP * NA;        // output 1: surroundresponse
    float* pn   = out + 2 * (size_t)NP * NA;    // output 2: predicted_neural
    float* pv   = out + 3 * (size_t)NP * NA;    // output 3: predicted_voxel

    float* gtab = (float*)d_ws;                      // 3*2*4096*64 floats (6 MB)
    float* attf = gtab + 3 * 2 * (size_t)NP * 64;    // 4096 floats

    setup_kernel<<<NP, 64, 0, stream>>>(pscale, pasig, pagain, pssf, psff,
                                        gtab, attf);

    const float* gx0 = gtab;
    const float* gy0 = gx0 + (size_t)NP * 64;
    const float* gx1 = gtab + 2 * (size_t)NP * 64;
    const float* gy1 = gx1 + (size_t)NP * 64;
    const float* gx2 = gtab + 4 * (size_t)NP * 64;
    const float* gy2 = gx2 + (size_t)NP * 64;

    dim3 grid(NP / BP, NA / BA);   // 128 x 2 = 256 blocks
    field_gemm<0><<<grid, 256, 0, stream>>>(gx0, gy0, stim, attf, nullptr,
                                            num, nullptr);
    field_gemm<1><<<grid, 256, 0, stream>>>(gx1, gy1, num, nullptr, num,
                                            surr, pn);
    field_gemm<2><<<grid, 256, 0, stream>>>(gx2, gy2, pn, nullptr, nullptr,
                                            pv, nullptr);
}

// Round 2
// 89.568 us; speedup vs baseline: 6.2715x; 6.2715x over previous
//
#include <hip/hip_runtime.h>
#include <hip/hip_bf16.h>
#include <math.h>

#define NP 4096     // GRID*GRID
#define NA 256      // stim channels

typedef unsigned short ushort_t;
typedef __attribute__((ext_vector_type(8))) short short8;
typedef __attribute__((ext_vector_type(4))) float f32x4;
typedef __attribute__((ext_vector_type(4))) unsigned short ushort4v;
typedef __attribute__((ext_vector_type(8))) unsigned short ushort8v;

__device__ __forceinline__ ushort_t f2bf(float x) {
    __hip_bfloat16 h = __float2bfloat16(x);
    return *reinterpret_cast<ushort_t*>(&h);
}

// ---------------------------------------------------------------------------
// Setup: per-p 1D Gaussian tables (normalization folded in) + attention field.
// gtab layout: [field f=0(rf),1(ss),2(sf)] [x=0,y=1] [p:4096] [idx:64]  (f32)
// ---------------------------------------------------------------------------
__global__ void setup_kernel(const float* __restrict__ pscale,
                             const float* __restrict__ pasig,
                             const float* __restrict__ pagain,
                             const float* __restrict__ pssf,
                             const float* __restrict__ psff,
                             float* __restrict__ gtab,
                             float* __restrict__ attf)
{
    int p = blockIdx.x;
    int j = threadIdx.x;      // 0..63
    const float step = 20.0f / 63.0f;
    float cx = -10.0f + step * (float)(p & 63);
    float cy = -10.0f + step * (float)(p >> 6);
    float coord = -10.0f + step * (float)j;

    float sig0 = 0.07f + pscale[0] * sqrtf(cx * cx + cy * cy);
    float fac1 = pssf[0], fac2 = psff[0];

    float dx = coord - cx;
    float dy = coord - cy;

    #pragma unroll
    for (int f = 0; f < 3; ++f) {
        float s = sig0 * (f == 0 ? 1.0f : (f == 1 ? fac1 : fac2));
        float inv = 1.0f / (2.0f * s * s);
        float gx = expf(-dx * dx * inv);
        float gy = expf(-dy * dy * inv);
        float sx = gx, sy = gy;
        #pragma unroll
        for (int off = 32; off > 0; off >>= 1) {
            sx += __shfl_down(sx, off);
            sy += __shfl_down(sy, off);
        }
        sx = __shfl(sx, 0);
        sy = __shfl(sy, 0);
        float* bx = gtab + (size_t)f * 2 * NP * 64;
        bx[p * 64 + j] = gx / sx;            // gxn[p][j]
        bx[(size_t)NP * 64 + p * 64 + j] = gy / sy;  // gyn[p][i]
    }
    if (j == 0) {
        float as = pasig[0];
        float d2 = (cx - 3.0f) * (cx - 3.0f) + cy * cy;
        attf[p] = pagain[0] * expf(-d2 / (2.0f * as * as)) + 1.0f;
    }
}

// ---------------------------------------------------------------------------
// Transpose stim [4096 g][256 a] f32 -> stimT [256 a][4096 g] bf16
// ---------------------------------------------------------------------------
__global__ __launch_bounds__(256)
void transpose_bf16(const float* __restrict__ in, ushort_t* __restrict__ out)
{
    __shared__ float lt[64][65];
    int g0 = blockIdx.x * 64, a0 = blockIdx.y * 64;
    int t = threadIdx.x;
    int ar = (t & 15) * 4, gr = t >> 4;           // gr 0..15
    #pragma unroll
    for (int k = 0; k < 4; ++k) {
        float4 v = *(const float4*)&in[(size_t)(g0 + gr + 16 * k) * NA + a0 + ar];
        lt[gr + 16 * k][ar + 0] = v.x;
        lt[gr + 16 * k][ar + 1] = v.y;
        lt[gr + 16 * k][ar + 2] = v.z;
        lt[gr + 16 * k][ar + 3] = v.w;
    }
    __syncthreads();
    int a = t & 63, c = t >> 6;                   // c 0..3
    ushort8v u0, u1;
    #pragma unroll
    for (int i = 0; i < 8; ++i) u0[i] = f2bf(lt[c * 16 + i][a]);
    #pragma unroll
    for (int i = 0; i < 8; ++i) u1[i] = f2bf(lt[c * 16 + 8 + i][a]);
    ushort_t* dst = out + (size_t)(a0 + a) * NP + g0 + c * 16;
    *(ushort8v*)dst = u0;
    *(ushort8v*)(dst + 8) = u1;
}

// ---------------------------------------------------------------------------
// C[p,a] = sum_g F[g,p]*B[g,a];  F[g,p] = gyn[p][g>>6]*gxn[p][g&63]
// MFMA 16x16x32 bf16. A-operand = gxn frags in REGISTERS (constant over K);
// gyn applied to the accumulator (per-lane rows share the scale).
// B^T bf16 staged global->LDS via global_load_lds w/ pre-swizzled source.
// Block: 512 thr = 8 waves = 4 n-groups x 2 K-halves. Tile 64p x 64a.
// Grid (64, 4) = 256 blocks.
// MODE 0: C=dot*attf[p], CT=bf16(C)^T         (numerator, numT)
// MODE 1: C=dot(surr); C2=num/(dot+0.5)(pn); CT=bf16(pn)^T
// MODE 2: C=dot                               (predicted_voxel)
// ---------------------------------------------------------------------------
template <int MODE>
__global__ __launch_bounds__(512)
void field_gemm(const float* __restrict__ gxn,   // [4096][64]
                const float* __restrict__ gyn,   // [4096][64]
                const ushort_t* __restrict__ bT, // [256][4096] bf16
                const float* __restrict__ attf,
                const float* __restrict__ num,
                float* __restrict__ C,
                float* __restrict__ C2,
                ushort_t* __restrict__ CT)
{
    // lB physical layout per half: row n (64 rows) * 64 ushort (128B);
    // logical k-slot s stored at physical slot s ^ (n&7) (16B slots).
    __shared__ ushort_t lB[2][2][64 * 64];
    __shared__ float lgyT[64][64];       // [gi][p-local]
    __shared__ float lred[4 * 64 * 17];  // k-half reduce scratch (padded)

    const int t   = threadIdx.x;
    const int w   = t >> 6;          // wave 0..7
    const int l   = t & 63;
    const int ng  = w >> 1;          // n-group 0..3
    const int kh  = w & 1;           // K-half
    const int r16 = l & 15;
    const int q   = l >> 4;          // 0..3
    const int p0  = blockIdx.x * 64;
    const int a0  = blockIdx.y * 64;

    // stage gyn^T tile: lgyT[gi][pl]  (global reads strided but L2-hot, one-time)
    for (int idx = t; idx < 4096; idx += 512) {
        int gi = idx >> 6, pl = idx & 63;
        lgyT[gi][pl] = gyn[(size_t)(p0 + pl) * 64 + gi];
    }

    // A-fragments: ax[fm][c] = bf16 gxn[p0+fm*16+r16][c*32 + q*8 + j], j=0..7
    short8 ax[4][2];
    #pragma unroll
    for (int fm = 0; fm < 4; ++fm) {
        const float* rowp = gxn + (size_t)(p0 + fm * 16 + r16) * 64;
        #pragma unroll
        for (int c = 0; c < 2; ++c) {
            float4 v0 = *(const float4*)(rowp + c * 32 + q * 8);
            float4 v1 = *(const float4*)(rowp + c * 32 + q * 8 + 4);
            short8 av;
            av[0] = (short)f2bf(v0.x); av[1] = (short)f2bf(v0.y);
            av[2] = (short)f2bf(v0.z); av[3] = (short)f2bf(v0.w);
            av[4] = (short)f2bf(v1.x); av[5] = (short)f2bf(v1.y);
            av[6] = (short)f2bf(v1.z); av[7] = (short)f2bf(v1.w);
            ax[fm][c] = av;
        }
    }

    // DMA stage: wave w stages rows w*8..w*8+7 of each half for K-pair tt.
    // Source address carries the inverse swizzle; LDS dest is linear.
    const int srow = l >> 3;                       // 0..7 within wave's rows
    const int sslot = (l & 7) ^ (srow & 7);        // logical slot for this lane
    #define STAGE(buf, tt)                                                      \
        _Pragma("unroll")                                                       \
        for (int h = 0; h < 2; ++h) {                                           \
            const ushort_t* src = bT + (size_t)(a0 + w * 8 + srow) * NP         \
                                  + (2 * (tt) + h) * 64 + sslot * 8;            \
            ushort_t* dst = &lB[buf][h][(w * 8) * 64];                          \
            __builtin_amdgcn_global_load_lds(                                   \
                (const __attribute__((address_space(1))) unsigned int*)src,     \
                (__attribute__((address_space(3))) unsigned int*)dst, 16, 0, 0);\
        }

    f32x4 acc[4];
    #pragma unroll
    for (int fm = 0; fm < 4; ++fm) acc[fm] = (f32x4){0.f, 0.f, 0.f, 0.f};

    STAGE(0, 0);
    __syncthreads();   // drains vmcnt before first use

    const int n = ng * 16 + r16;                   // this lane's B column
    const ushort_t* lbase = &lB[0][kh][0];
    const int bo0 = n * 64 + ((q ^ (n & 7)) * 8);        // chunk 0 slot
    const int bo1 = n * 64 + (((4 + q) ^ (n & 7)) * 8);  // chunk 1 slot

    for (int tt = 0; tt < 32; ++tt) {
        int buf = tt & 1;
        if (tt < 31) { STAGE(buf ^ 1, tt + 1); }
        const ushort_t* bb = lbase + buf * 2 * 64 * 64;
        short8 b0 = *(const short8*)(bb + bo0);
        short8 b1 = *(const short8*)(bb + bo1);
        int gi = 2 * tt + kh;
        #pragma unroll
        for (int fm = 0; fm < 4; ++fm) {
            f32x4 tmp = (f32x4){0.f, 0.f, 0.f, 0.f};
            tmp = __builtin_amdgcn_mfma_f32_16x16x32_bf16(ax[fm][0], b0, tmp, 0, 0, 0);
            tmp = __builtin_amdgcn_mfma_f32_16x16x32_bf16(ax[fm][1], b1, tmp, 0, 0, 0);
            f32x4 s = *(const f32x4*)&lgyT[gi][fm * 16 + q * 4];
            acc[fm] += s * tmp;
        }
        __syncthreads();
    }

    // ---- reduce the two K-halves ----
    if (kh == 1) {
        float* dst = &lred[(ng * 64 + l) * 17];
        #pragma unroll
        for (int fm = 0; fm < 4; ++fm)
            #pragma unroll
            for (int r = 0; r < 4; ++r) dst[fm * 4 + r] = acc[fm][r];
    }
    __syncthreads();
    if (kh == 0) {
        const float* src = &lred[(ng * 64 + l) * 17];
        #pragma unroll
        for (int fm = 0; fm < 4; ++fm)
            #pragma unroll
            for (int r = 0; r < 4; ++r) acc[fm][r] += src[fm * 4 + r];

        // ---- epilogue ----
        int a = a0 + ng * 16 + r16;
        #pragma unroll
        for (int fm = 0; fm < 4; ++fm) {
            int pr = p0 + fm * 16 + q * 4;
            if (MODE == 0) {
                ushort4v tv;
                #pragma unroll
                for (int r = 0; r < 4; ++r) {
                    float v = acc[fm][r] * attf[pr + r];
                    C[(size_t)(pr + r) * NA + a] = v;
                    tv[r] = f2bf(v);
                }
                *(ushort4v*)&CT[(size_t)a * NP + pr] = tv;
            } else if (MODE == 1) {
                ushort4v tv;
                #pragma unroll
                for (int r = 0; r < 4; ++r) {
                    float sres = acc[fm][r];
                    C[(size_t)(pr + r) * NA + a] = sres;            // surround
                    float nv = num[(size_t)(pr + r) * NA + a];
                    float pnv = nv / (sres + 0.5f);
                    C2[(size_t)(pr + r) * NA + a] = pnv;            // pred_neural
                    tv[r] = f2bf(pnv);
                }
                *(ushort4v*)&CT[(size_t)a * NP + pr] = tv;
            } else {
                #pragma unroll
                for (int r = 0; r < 4; ++r)
                    C[(size_t)(pr + r) * NA + a] = acc[fm][r];      // pred_voxel
            }
        }
    }
}

extern "C" void kernel_launch(void* const* d_in, const int* in_sizes, int n_in,
                              void* d_out, int out_size, void* d_ws, size_t ws_size,
                              hipStream_t stream)
{
    const float* stim   = (const float*)d_in[0];
    const float* pscale = (const float*)d_in[1];
    const float* pasig  = (const float*)d_in[2];
    const float* pagain = (const float*)d_in[3];
    const float* pssf   = (const float*)d_in[4];
    const float* psff   = (const float*)d_in[5];

    float* out  = (float*)d_out;
    float* num  = out;
    float* surr = out + (size_t)NP * NA;
    float* pn   = out + 2 * (size_t)NP * NA;
    float* pv   = out + 3 * (size_t)NP * NA;

    // ws layout
    float*    gtab  = (float*)d_ws;                        // 3*2*NP*64 f32 (6.3 MB)
    float*    attf  = gtab + 3 * 2 * (size_t)NP * 64;      // NP f32
    ushort_t* stimT = (ushort_t*)(attf + NP);              // NA*NP bf16 (2 MB)
    ushort_t* numT  = stimT + (size_t)NA * NP;             // 2 MB
    ushort_t* pnT   = numT + (size_t)NA * NP;              // 2 MB

    const float* gx0 = gtab;
    const float* gy0 = gx0 + (size_t)NP * 64;
    const float* gx1 = gtab + 2 * (size_t)NP * 64;
    const float* gy1 = gx1 + (size_t)NP * 64;
    const float* gx2 = gtab + 4 * (size_t)NP * 64;
    const float* gy2 = gx2 + (size_t)NP * 64;

    setup_kernel<<<NP, 64, 0, stream>>>(pscale, pasig, pagain, pssf, psff,
                                        gtab, attf);
    transpose_bf16<<<dim3(64, 4), 256, 0, stream>>>(stim, stimT);

    dim3 g(64, 4);
    field_gemm<0><<<g, 512, 0, stream>>>(gx0, gy0, stimT, attf, nullptr,
                                         num, nullptr, numT);
    field_gemm<1><<<g, 512, 0, stream>>>(gx1, gy1, numT, nullptr, num,
                                         surr, pn, pnT);
    field_gemm<2><<<g, 512, 0, stream>>>(gx2, gy2, pnT, nullptr, nullptr,
                                         pv, nullptr, nullptr);
}